// Round 7
// baseline (245.431 us; speedup 1.0000x reference)
//
#include <hip/hip_runtime.h>
#include <cstddef>

#define CC 128
#define NH 8
#define HD 16
#define DDIM 31
#define HWW 1024
#define TOK 31744   // DDIM * HWW
#define SCALE2 0.0625f   // (HD^-0.5)^2 — both QK^T operands pre-scaled in the ref

typedef __attribute__((ext_vector_type(4))) short  short4v;
typedef __attribute__((ext_vector_type(4))) float  float4v;

__device__ inline unsigned bf16rne(float f) {
    unsigned u = __float_as_uint(f);
    return (u + 0x7fffu + ((u >> 16) & 1u)) >> 16;
}
__device__ inline float bf2f(unsigned h) { return __uint_as_float(h << 16); }

// ---------------------------------------------------------------------------
// Kernel 0: prep (weights only).
//  blocks 0-63:    transpose+split {Wq1,Wq2,Wp1,Wp2} to bf16 hi/lo planes.
//  blocks 64-191:  gate fold: Wc[k][c]      = sum_j Wp1[k][j]*Wg[j][c]
//                             Wc[128+k][c]  = sum_j Wp2[k][j]*Wg[128+j][c]
//  block 192:      bc[c] = bg[c] + sum_j bp1[j]*Wg[j][c] + bp2[j]*Wg[128+j][c]
// ---------------------------------------------------------------------------
__global__ __launch_bounds__(256) void prep_kernel(
    const float* __restrict__ Wq1, const float* __restrict__ Wq2,
    const float* __restrict__ Wp1, const float* __restrict__ Wp2,
    const float* __restrict__ Wg,  const float* __restrict__ bp1,
    const float* __restrict__ bp2, const float* __restrict__ bg,
    ushort* __restrict__ wsp, float* __restrict__ Wc, float* __restrict__ bc)
{
    const int b = blockIdx.x, tid = threadIdx.x;
    if (b < 64) {
        const int mat = b >> 4;
        const int idx = ((b & 15) * 256 + tid) * 4;  // k*128 + co
        const float* W = mat == 0 ? Wq1 : mat == 1 ? Wq2 : mat == 2 ? Wp1 : Wp2;
        ushort* hi = wsp + (size_t)mat * 2 * CC * CC;
        ushort* lo = hi + CC * CC;
        const int k = idx >> 7, co = idx & 127;
        float4 w = *(const float4*)&W[idx];
        float wv[4] = {w.x, w.y, w.z, w.w};
#pragma unroll
        for (int e = 0; e < 4; ++e) {
            unsigned h = bf16rne(wv[e]);
            unsigned lw = bf16rne(wv[e] - bf2f(h));
            hi[(co + e) * CC + k] = (ushort)h;
            lo[(co + e) * CC + k] = (ushort)lw;
        }
    } else if (b < 192) {
        const int kb = b - 64;
        const int c = tid & 127;
        const float* Wp  = (tid < 128) ? Wp1 : Wp2;
        const float* Wgp = (tid < 128) ? Wg  : Wg + (size_t)CC * CC;
        float a = 0.f;
        for (int j = 0; j < CC; ++j) a += Wp[kb * CC + j] * Wgp[j * CC + c];
        Wc[((tid < 128 ? 0 : CC) + kb) * CC + c] = a;
    } else {
        if (tid < CC) {
            float a = bg[tid];
            for (int j = 0; j < CC; ++j)
                a += bp1[j] * Wg[j * CC + tid] + bp2[j] * Wg[(CC + j) * CC + tid];
            bc[tid] = a;
        }
    }
}

// ---------------------------------------------------------------------------
// Kernel 1: Q projection, BOTH branches per block (x staged once).
// q_b[t][co] = sum_ci x[ci][t] * Wq_b[ci][co] + bq_b[co]
// W A-frags from pre-split global; x staged transposed+split in LDS.
// ---------------------------------------------------------------------------
#define AST 132   // LDS act row stride (ushorts)
__global__ __launch_bounds__(512, 4) void qproj_kernel(
    const float* __restrict__ x, const ushort* __restrict__ wsp,
    const float* __restrict__ bq1, const float* __restrict__ bq2,
    float* __restrict__ q1, float* __restrict__ q2)
{
    __shared__ ushort Ahi[CC * AST], Alo[CC * AST];   // [t][ci], 67.6 KB
    const int tid = threadIdx.x;
    const int t0  = blockIdx.x * 128;

    // stage x tile transposed + split: [t][ci] (once, shared by both branches)
    for (int i = tid; i < CC * 128 / 4; i += 512) {
        int t4 = i & 31, ci = i >> 5;
        float4 v = *(const float4*)&x[(size_t)ci * TOK + t0 + t4 * 4];
        float xv[4] = {v.x, v.y, v.z, v.w};
#pragma unroll
        for (int e = 0; e < 4; ++e) {
            unsigned h = bf16rne(xv[e]);
            unsigned lw = bf16rne(xv[e] - bf2f(h));
            Ahi[(t4 * 4 + e) * AST + ci] = (ushort)h;
            Alo[(t4 * 4 + e) * AST + ci] = (ushort)lw;
        }
    }
    __syncthreads();

    const int lane = tid & 63;
    const int l    = lane & 15;
    const int quad = lane >> 4;
    const int co0  = (tid >> 6) * 16;

    for (int branch = 0; branch < 2; ++branch) {
        const ushort* Whi = wsp + (size_t)branch * 2 * CC * CC;
        const ushort* Wlo = Whi + CC * CC;
        short4v ah[8], al[8];
#pragma unroll
        for (int k8 = 0; k8 < 8; ++k8) {
            ah[k8] = *(const short4v*)&Whi[(co0 + l) * CC + k8 * 16 + quad * 4];
            al[k8] = *(const short4v*)&Wlo[(co0 + l) * CC + k8 * 16 + quad * 4];
        }
        float4v acc[8];
#pragma unroll
        for (int nt = 0; nt < 8; ++nt) acc[nt] = (float4v){0.f, 0.f, 0.f, 0.f};
#pragma unroll
        for (int k8 = 0; k8 < 8; ++k8) {
#pragma unroll
            for (int nt = 0; nt < 8; ++nt) {
                short4v bh = *(const short4v*)&Ahi[(nt * 16 + l) * AST + k8 * 16 + quad * 4];
                short4v bl = *(const short4v*)&Alo[(nt * 16 + l) * AST + k8 * 16 + quad * 4];
                acc[nt] = __builtin_amdgcn_mfma_f32_16x16x16bf16_1k(ah[k8], bh, acc[nt], 0, 0, 0);
                acc[nt] = __builtin_amdgcn_mfma_f32_16x16x16bf16_1k(ah[k8], bl, acc[nt], 0, 0, 0);
                acc[nt] = __builtin_amdgcn_mfma_f32_16x16x16bf16_1k(al[k8], bh, acc[nt], 0, 0, 0);
            }
        }
        const float* bq = branch ? bq2 : bq1;
        float* outp     = branch ? q2 : q1;
        float4 bv = *(const float4*)&bq[co0 + quad * 4];
        float bb[4] = {bv.x, bv.y, bv.z, bv.w};
#pragma unroll
        for (int nt = 0; nt < 8; ++nt) {
            int t = t0 + nt * 16 + l;
            float4 o = {acc[nt][0] + bb[0], acc[nt][1] + bb[1],
                        acc[nt][2] + bb[2], acc[nt][3] + bb[3]};
            *(float4*)&outp[(size_t)t * CC + co0 + quad * 4] = o;
        }
    }
}

// ---------------------------------------------------------------------------
// Kernel 2: FUSED attention — blocks 0-127 spectral (8 hw each), 128-375
// spatial ((d,h) slices). Rowsums via ones-MFMA: mfma(pf, ones) sums exactly
// the truncated bf16 P values in fp32 (same semantics as old persum, bias
// cancellation preserved) and lands the rowsum on the consuming lane — no
// v_and, no persum adds, no shfl. Gate column-sums fused. In-place.
// ---------------------------------------------------------------------------
#define QS2 132
#define QSS 20
#define QTP 1044
__global__ __launch_bounds__(1024, 8) void attn_kernel(
    float* __restrict__ q1, float* __restrict__ q2, float* __restrict__ sums)
{
    __shared__ __align__(16) ushort smem[HWW * QSS + HD * QTP];  // 74.4 KB
    __shared__ float fsum[CC];
    const int tid  = threadIdx.x;
    const int lane = tid & 63;
    const int l    = lane & 15;
    const int quad = lane >> 4;
    const float k2 = SCALE2 * 1.44269504f;
    const short4v onesb = {(short)0x3F80, (short)0x3F80, (short)0x3F80, (short)0x3F80};
    if (tid < CC) fsum[tid] = 0.f;

    if (blockIdx.x < 128) {
        // ---------------- spectral: 8 hw per block ----------------
        const int wave = tid >> 6;
        const int hwl  = wave >> 1;
        const int half = wave & 1;
        const int hw   = blockIdx.x * 8 + hwl;
        ushort* Q = smem + hwl * (32 * QS2);
        for (int it = 0; it < 8; ++it) {
            int idx = it * 64 + lane;
            int dd = half * 16 + (idx >> 5), c4 = idx & 31;
            if (dd < 31) {
                float4 v = *(const float4*)&q1[((size_t)dd * HWW + hw) * CC + c4 * 4];
                unsigned s0 = bf16rne(v.x), s1 = bf16rne(v.y);
                unsigned s2 = bf16rne(v.z), s3 = bf16rne(v.w);
                *(uint2*)&Q[dd * QS2 + c4 * 4] = make_uint2(s0 | (s1 << 16), s2 | (s3 << 16));
            }
        }
        if (half) for (int i = lane; i < 128; i += 64) Q[31 * QS2 + i] = 0;
        __syncthreads();

        const int hh = half * 4;
#pragma unroll
        for (int hl = 0; hl < 4; ++hl) {
            const int hc = (hh + hl) * HD;
            short4v qf[2];
            qf[0] = *(const short4v*)&Q[l * QS2 + hc + quad * 4];
            qf[1] = *(const short4v*)&Q[(16 + l) * QS2 + hc + quad * 4];
            short4v va[2];
#pragma unroll
            for (int j = 0; j < 2; ++j)
#pragma unroll
                for (int jj = 0; jj < 4; ++jj)
                    va[j][jj] = (short)Q[(j * 16 + quad * 4 + jj) * QS2 + hc + l];

            float4v o[2]   = {(float4v){0.f,0.f,0.f,0.f}, (float4v){0.f,0.f,0.f,0.f}};
            float4v osr[2] = {(float4v){0.f,0.f,0.f,0.f}, (float4v){0.f,0.f,0.f,0.f}};
#pragma unroll
            for (int j = 0; j < 2; ++j) {
#pragma unroll
                for (int i2 = 0; i2 < 2; ++i2) {
                    float4v s = __builtin_amdgcn_mfma_f32_16x16x16bf16_1k(
                        qf[j], qf[i2], (float4v){0.f,0.f,0.f,0.f}, 0, 0, 0);
                    unsigned u0 = __float_as_uint(__builtin_amdgcn_exp2f(s[0] * k2));
                    unsigned u1 = __float_as_uint(__builtin_amdgcn_exp2f(s[1] * k2));
                    unsigned u2 = __float_as_uint(__builtin_amdgcn_exp2f(s[2] * k2));
                    unsigned u3 = __float_as_uint(__builtin_amdgcn_exp2f(s[3] * k2));
                    if (j == 1 && quad == 3) u3 = 0;   // mask key 31
                    short4v pf;
                    pf[0] = (short)(u0 >> 16); pf[1] = (short)(u1 >> 16);
                    pf[2] = (short)(u2 >> 16); pf[3] = (short)(u3 >> 16);
                    o[i2]   = __builtin_amdgcn_mfma_f32_16x16x16bf16_1k(va[j], pf, o[i2], 0, 0, 0);
                    osr[i2] = __builtin_amdgcn_mfma_f32_16x16x16bf16_1k(onesb, pf, osr[i2], 0, 0, 0);
                }
            }
            float vsum[4] = {0.f, 0.f, 0.f, 0.f};
#pragma unroll
            for (int i2 = 0; i2 < 2; ++i2) {
                float inv = 1.f / osr[i2][0];   // rowsum(query=i2*16+l), this lane
                int dq = i2 * 16 + l;
                if (dq < 31) {
                    float4 ov = {o[i2][0]*inv, o[i2][1]*inv, o[i2][2]*inv, o[i2][3]*inv};
                    *(float4*)&q1[((size_t)dq * HWW + hw) * CC + hc + quad * 4] = ov;
#pragma unroll
                    for (int r = 0; r < 4; ++r) vsum[r] += o[i2][r] * inv;
                }
            }
#pragma unroll
            for (int r = 0; r < 4; ++r) {
                float v = vsum[r];
                v += __shfl_xor(v, 1); v += __shfl_xor(v, 2);
                v += __shfl_xor(v, 4); v += __shfl_xor(v, 8);
                if (l == 0) atomicAdd(&fsum[hc + quad * 4 + r], v);
            }
        }
        __syncthreads();
        if (tid < CC) atomicAdd(&sums[tid], fsum[tid]);
    } else {
        // ---------------- spatial: one (d,h) slice per block ----------------
        const int bidx = blockIdx.x - 128;
        const int d = bidx >> 3, h = bidx & 7;
        ushort* Qs  = smem;
        ushort* QTs = smem + HWW * QSS;
        const size_t base = (size_t)d * HWW * CC + h * HD;

        for (int i = tid; i < HWW * 4; i += 1024) {
            int row = i >> 2, q4 = i & 3;
            float4 v = *(const float4*)&q2[base + (size_t)row * CC + q4 * 4];
            unsigned s0 = bf16rne(v.x), s1 = bf16rne(v.y);
            unsigned s2 = bf16rne(v.z), s3 = bf16rne(v.w);
            *(uint2*)&Qs[row * QSS + q4 * 4] = make_uint2(s0 | (s1 << 16), s2 | (s3 << 16));
            QTs[(q4 * 4 + 0) * QTP + row] = (ushort)s0;
            QTs[(q4 * 4 + 1) * QTP + row] = (ushort)s1;
            QTs[(q4 * 4 + 2) * QTP + row] = (ushort)s2;
            QTs[(q4 * 4 + 3) * QTP + row] = (ushort)s3;
        }
        __syncthreads();

        const int Rw = (tid >> 6) * 64;
        short4v qf[4];
#pragma unroll
        for (int lt = 0; lt < 4; ++lt) {
            short4v raw = *(short4v*)&Qs[(Rw + lt * 16 + l) * QSS + quad * 4];
            short4v sc;
#pragma unroll
            for (int e = 0; e < 4; ++e) {
                float f = bf2f((unsigned)(ushort)raw[e]) * k2;
                sc[e] = (short)bf16rne(f);
            }
            qf[lt] = sc;
        }

        float4v acc[4], accs[4];
#pragma unroll
        for (int lt = 0; lt < 4; ++lt) {
            acc[lt]  = (float4v){0.f, 0.f, 0.f, 0.f};
            accs[lt] = (float4v){0.f, 0.f, 0.f, 0.f};
        }

#pragma unroll 2
        for (int mt = 0; mt < 64; ++mt) {
            const int m0 = mt * 16;
            short4v ka = *(short4v*)&Qs[(m0 + l) * QSS + quad * 4];
            short4v vb = *(short4v*)&QTs[l * QTP + m0 + quad * 4];
#pragma unroll
            for (int lt = 0; lt < 4; ++lt) {
                float4v s = __builtin_amdgcn_mfma_f32_16x16x16bf16_1k(
                    ka, qf[lt], (float4v){0.f, 0.f, 0.f, 0.f}, 0, 0, 0);
                unsigned u0 = __float_as_uint(__builtin_amdgcn_exp2f(s[0]));
                unsigned u1 = __float_as_uint(__builtin_amdgcn_exp2f(s[1]));
                unsigned u2 = __float_as_uint(__builtin_amdgcn_exp2f(s[2]));
                unsigned u3 = __float_as_uint(__builtin_amdgcn_exp2f(s[3]));
                short4v pf;
                pf[0] = (short)(u0 >> 16); pf[1] = (short)(u1 >> 16);
                pf[2] = (short)(u2 >> 16); pf[3] = (short)(u3 >> 16);
                acc[lt]  = __builtin_amdgcn_mfma_f32_16x16x16bf16_1k(pf, vb, acc[lt], 0, 0, 0);
                accs[lt] = __builtin_amdgcn_mfma_f32_16x16x16bf16_1k(pf, onesb, accs[lt], 0, 0, 0);
            }
        }

        float osum = 0.f;
#pragma unroll
        for (int lt = 0; lt < 4; ++lt) {
#pragma unroll
            for (int reg = 0; reg < 4; ++reg) {
                float val = acc[lt][reg] / accs[lt][reg];   // rowsum on this lane
                int row = Rw + lt * 16 + quad * 4 + reg;
                q2[base + (size_t)row * CC + l] = val;
                osum += val;
            }
        }
        osum += __shfl_xor(osum, 16);
        osum += __shfl_xor(osum, 32);
        if (quad == 0) atomicAdd(&fsum[l], osum);
        __syncthreads();
        if (tid < HD) atomicAdd(&sums[CC + h * HD + tid], fsum[tid]);
    }
}

// ---------------------------------------------------------------------------
// Kernel 3: gate via folded Wc/bc: g = sigmoid((sums·Wc)/TOK + bc).
// 512 threads: 4 k-chunks of 64 per output channel.
// ---------------------------------------------------------------------------
__global__ __launch_bounds__(512) void gate_kernel(
    const float* __restrict__ sums, const float* __restrict__ Wc,
    const float* __restrict__ bc, float* __restrict__ gate)
{
    __shared__ float pa[4][CC];
    const int tid = threadIdx.x;
    const int part = tid >> 7;
    const int c = tid & 127;
    float a = 0.f;
    for (int kk = 0; kk < 64; ++kk) {
        int k = part * 64 + kk;
        a += sums[k] * Wc[(size_t)k * CC + c];
    }
    pa[part][c] = a;
    __syncthreads();
    if (part == 0) {
        float g = (pa[0][c] + pa[1][c] + pa[2][c] + pa[3][c]) * (1.f / (float)TOK) + bc[c];
        gate[c] = 1.f / (1.f + __expf(-g));
    }
}

// ---------------------------------------------------------------------------
// Kernel 4: output projection, BOTH branches per block, 64-token tiles.
// out[co][t] = g*(q1@Wp1 + bp1) + (1-g)*(q2@Wp2 + bp2)
// ---------------------------------------------------------------------------
__global__ __launch_bounds__(512, 4) void oproj_kernel(
    const float* __restrict__ q1, const float* __restrict__ q2,
    const ushort* __restrict__ wsp,
    const float* __restrict__ bp1, const float* __restrict__ bp2,
    const float* __restrict__ gatev, float* __restrict__ out)
{
    __shared__ ushort Ahi[64 * AST], Alo[64 * AST];   // 33.8 KB
    const int tid = threadIdx.x;
    const int t0  = blockIdx.x * 64;
    const int lane = tid & 63;
    const int l    = lane & 15;
    const int quad = lane >> 4;
    const int co0  = (tid >> 6) * 16;

    float4v acc[2][4];
#pragma unroll
    for (int br = 0; br < 2; ++br)
#pragma unroll
        for (int nt = 0; nt < 4; ++nt) acc[br][nt] = (float4v){0.f, 0.f, 0.f, 0.f};

    for (int br = 0; br < 2; ++br) {
        const float* act = br ? q2 : q1;
        const ushort* Whi = wsp + (size_t)(2 + br) * 2 * CC * CC;
        const ushort* Wlo = Whi + CC * CC;
        short4v ah[8], al[8];
#pragma unroll
        for (int k8 = 0; k8 < 8; ++k8) {
            ah[k8] = *(const short4v*)&Whi[(co0 + l) * CC + k8 * 16 + quad * 4];
            al[k8] = *(const short4v*)&Wlo[(co0 + l) * CC + k8 * 16 + quad * 4];
        }
        __syncthreads();
        for (int i = tid; i < 64 * CC / 4; i += 512) {
            int k4 = i & 31, t = i >> 5;
            float4 v = *(const float4*)&act[(size_t)(t0 + t) * CC + k4 * 4];
            float xv[4] = {v.x, v.y, v.z, v.w};
            unsigned hi[4], lo[4];
#pragma unroll
            for (int e = 0; e < 4; ++e) {
                hi[e] = bf16rne(xv[e]);
                lo[e] = bf16rne(xv[e] - bf2f(hi[e]));
            }
            *(uint2*)&Ahi[t * AST + k4 * 4] = make_uint2(hi[0] | (hi[1] << 16), hi[2] | (hi[3] << 16));
            *(uint2*)&Alo[t * AST + k4 * 4] = make_uint2(lo[0] | (lo[1] << 16), lo[2] | (lo[3] << 16));
        }
        __syncthreads();
#pragma unroll
        for (int k8 = 0; k8 < 8; ++k8) {
#pragma unroll
            for (int nt = 0; nt < 4; ++nt) {
                short4v bh = *(const short4v*)&Ahi[(nt * 16 + l) * AST + k8 * 16 + quad * 4];
                short4v bl = *(const short4v*)&Alo[(nt * 16 + l) * AST + k8 * 16 + quad * 4];
                acc[br][nt] = __builtin_amdgcn_mfma_f32_16x16x16bf16_1k(ah[k8], bh, acc[br][nt], 0, 0, 0);
                acc[br][nt] = __builtin_amdgcn_mfma_f32_16x16x16bf16_1k(ah[k8], bl, acc[br][nt], 0, 0, 0);
                acc[br][nt] = __builtin_amdgcn_mfma_f32_16x16x16bf16_1k(al[k8], bh, acc[br][nt], 0, 0, 0);
            }
        }
    }

    float4 b1 = *(const float4*)&bp1[co0 + quad * 4];
    float4 b2 = *(const float4*)&bp2[co0 + quad * 4];
    float4 gv = *(const float4*)&gatev[co0 + quad * 4];
    float bb1[4] = {b1.x, b1.y, b1.z, b1.w};
    float bb2[4] = {b2.x, b2.y, b2.z, b2.w};
    float gg[4]  = {gv.x, gv.y, gv.z, gv.w};
#pragma unroll
    for (int nt = 0; nt < 4; ++nt) {
        int t = t0 + nt * 16 + l;
#pragma unroll
        for (int reg = 0; reg < 4; ++reg) {
            size_t idx = (size_t)(co0 + quad * 4 + reg) * TOK + t;
            out[idx] = gg[reg] * (acc[0][nt][reg] + bb1[reg]) +
                       (1.f - gg[reg]) * (acc[1][nt][reg] + bb2[reg]);
        }
    }
}

extern "C" void kernel_launch(void* const* d_in, const int* in_sizes, int n_in,
                              void* d_out, int out_size, void* d_ws, size_t ws_size,
                              hipStream_t stream)
{
    const float* x   = (const float*)d_in[0];
    const float* Wq1 = (const float*)d_in[1];
    const float* bq1 = (const float*)d_in[2];
    const float* Wp1 = (const float*)d_in[3];
    const float* bp1 = (const float*)d_in[4];
    const float* Wq2 = (const float*)d_in[5];
    const float* bq2 = (const float*)d_in[6];
    const float* Wp2 = (const float*)d_in[7];
    const float* bp2 = (const float*)d_in[8];
    const float* Wg  = (const float*)d_in[9];
    const float* bg  = (const float*)d_in[10];
    float* out = (float*)d_out;

    float*  q1   = (float*)d_ws;                 // spec q / attn-out (in-place)
    float*  q2   = q1 + (size_t)TOK * CC;        // spat q / attn-out (in-place)
    float*  sums = q2 + (size_t)TOK * CC;        // 256 floats
    float*  gate = sums + 2 * CC;                // 128 floats
    ushort* wsp  = (ushort*)(gate + CC);         // 4 x 2 x 128 x 128 ushorts
    float*  Wc   = (float*)(wsp + 4 * 2 * CC * CC);  // 256 x 128 floats
    float*  bc   = Wc + 2 * CC * CC;             // 128 floats

    hipMemsetAsync(sums, 0, 2 * CC * sizeof(float), stream);
    prep_kernel<<<dim3(193), 256, 0, stream>>>(Wq1, Wq2, Wp1, Wp2, Wg, bp1, bp2, bg,
                                               wsp, Wc, bc);
    qproj_kernel<<<dim3(248), 512, 0, stream>>>(x, wsp, bq1, bq2, q1, q2);
    attn_kernel<<<dim3(376), 1024, 0, stream>>>(q1, q2, sums);
    gate_kernel<<<1, 512, 0, stream>>>(sums, Wc, bc, gate);
    oproj_kernel<<<dim3(496), 512, 0, stream>>>(q1, q2, wsp, bp1, bp2, gate, out);
}

// Round 8
// 213.029 us; speedup vs baseline: 1.1521x; 1.1521x over previous
//
#include <hip/hip_runtime.h>
#include <cstddef>

#define CC 128
#define NH 8
#define HD 16
#define DDIM 31
#define HWW 1024
#define TOK 31744   // DDIM * HWW
#define SCALE2 0.0625f   // (HD^-0.5)^2 — both QK^T operands pre-scaled in the ref

typedef __attribute__((ext_vector_type(4))) short  short4v;
typedef __attribute__((ext_vector_type(4))) float  float4v;

__device__ inline unsigned bf16rne(float f) {
    unsigned u = __float_as_uint(f);
    return (u + 0x7fffu + ((u >> 16) & 1u)) >> 16;
}
__device__ inline float bf2f(unsigned h) { return __uint_as_float(h << 16); }

// ---------------------------------------------------------------------------
// Kernel 0: prep (weights only).
//  blocks 0-63:    transpose+split {Wq1,Wq2,Wp1,Wp2} to bf16 hi/lo planes.
//  blocks 64-191:  gate fold: Wc[k][c]      = sum_j Wp1[k][j]*Wg[j][c]
//                             Wc[128+k][c]  = sum_j Wp2[k][j]*Wg[128+j][c]
//  block 192:      bc[c] = bg[c] + sum_j bp1[j]*Wg[j][c] + bp2[j]*Wg[128+j][c]
// ---------------------------------------------------------------------------
__global__ __launch_bounds__(256) void prep_kernel(
    const float* __restrict__ Wq1, const float* __restrict__ Wq2,
    const float* __restrict__ Wp1, const float* __restrict__ Wp2,
    const float* __restrict__ Wg,  const float* __restrict__ bp1,
    const float* __restrict__ bp2, const float* __restrict__ bg,
    ushort* __restrict__ wsp, float* __restrict__ Wc, float* __restrict__ bc)
{
    const int b = blockIdx.x, tid = threadIdx.x;
    if (b < 64) {
        const int mat = b >> 4;
        const int idx = ((b & 15) * 256 + tid) * 4;  // k*128 + co
        const float* W = mat == 0 ? Wq1 : mat == 1 ? Wq2 : mat == 2 ? Wp1 : Wp2;
        ushort* hi = wsp + (size_t)mat * 2 * CC * CC;
        ushort* lo = hi + CC * CC;
        const int k = idx >> 7, co = idx & 127;
        float4 w = *(const float4*)&W[idx];
        float wv[4] = {w.x, w.y, w.z, w.w};
#pragma unroll
        for (int e = 0; e < 4; ++e) {
            unsigned h = bf16rne(wv[e]);
            unsigned lw = bf16rne(wv[e] - bf2f(h));
            hi[(co + e) * CC + k] = (ushort)h;
            lo[(co + e) * CC + k] = (ushort)lw;
        }
    } else if (b < 192) {
        const int kb = b - 64;
        const int c = tid & 127;
        const float* Wp  = (tid < 128) ? Wp1 : Wp2;
        const float* Wgp = (tid < 128) ? Wg  : Wg + (size_t)CC * CC;
        float a = 0.f;
        for (int j = 0; j < CC; ++j) a += Wp[kb * CC + j] * Wgp[j * CC + c];
        Wc[((tid < 128 ? 0 : CC) + kb) * CC + c] = a;
    } else {
        if (tid < CC) {
            float a = bg[tid];
            for (int j = 0; j < CC; ++j)
                a += bp1[j] * Wg[j * CC + tid] + bp2[j] * Wg[(CC + j) * CC + tid];
            bc[tid] = a;
        }
    }
}

// ---------------------------------------------------------------------------
// Kernel 1: Q projection, BOTH branches per block (x staged once).
// q_b[t][co] = sum_ci x[ci][t] * Wq_b[ci][co] + bq_b[co]
// W A-frags from pre-split global; x staged transposed+split in LDS.
// __launch_bounds__(512,2): VGPR budget 256 — the (512,4)=64-VGPR cap made
// the compiler spill the accumulators (r7: 310 MB scratch traffic/dispatch).
// LDS (67.6 KB) is the occupancy limiter at 2 blocks/CU regardless.
// ---------------------------------------------------------------------------
#define AST 132   // LDS act row stride (ushorts)
__global__ __launch_bounds__(512, 2) void qproj_kernel(
    const float* __restrict__ x, const ushort* __restrict__ wsp,
    const float* __restrict__ bq1, const float* __restrict__ bq2,
    float* __restrict__ q1, float* __restrict__ q2)
{
    __shared__ ushort Ahi[CC * AST], Alo[CC * AST];   // [t][ci], 67.6 KB
    const int tid = threadIdx.x;
    const int t0  = blockIdx.x * 128;

    // stage x tile transposed + split: [t][ci] (once, shared by both branches)
    for (int i = tid; i < CC * 128 / 4; i += 512) {
        int t4 = i & 31, ci = i >> 5;
        float4 v = *(const float4*)&x[(size_t)ci * TOK + t0 + t4 * 4];
        float xv[4] = {v.x, v.y, v.z, v.w};
#pragma unroll
        for (int e = 0; e < 4; ++e) {
            unsigned h = bf16rne(xv[e]);
            unsigned lw = bf16rne(xv[e] - bf2f(h));
            Ahi[(t4 * 4 + e) * AST + ci] = (ushort)h;
            Alo[(t4 * 4 + e) * AST + ci] = (ushort)lw;
        }
    }
    __syncthreads();

    const int lane = tid & 63;
    const int l    = lane & 15;
    const int quad = lane >> 4;
    const int co0  = (tid >> 6) * 16;

    for (int branch = 0; branch < 2; ++branch) {
        const ushort* Whi = wsp + (size_t)branch * 2 * CC * CC;
        const ushort* Wlo = Whi + CC * CC;
        short4v ah[8], al[8];
#pragma unroll
        for (int k8 = 0; k8 < 8; ++k8) {
            ah[k8] = *(const short4v*)&Whi[(co0 + l) * CC + k8 * 16 + quad * 4];
            al[k8] = *(const short4v*)&Wlo[(co0 + l) * CC + k8 * 16 + quad * 4];
        }
        float4v acc[8];
#pragma unroll
        for (int nt = 0; nt < 8; ++nt) acc[nt] = (float4v){0.f, 0.f, 0.f, 0.f};
#pragma unroll
        for (int k8 = 0; k8 < 8; ++k8) {
#pragma unroll
            for (int nt = 0; nt < 8; ++nt) {
                short4v bh = *(const short4v*)&Ahi[(nt * 16 + l) * AST + k8 * 16 + quad * 4];
                short4v bl = *(const short4v*)&Alo[(nt * 16 + l) * AST + k8 * 16 + quad * 4];
                acc[nt] = __builtin_amdgcn_mfma_f32_16x16x16bf16_1k(ah[k8], bh, acc[nt], 0, 0, 0);
                acc[nt] = __builtin_amdgcn_mfma_f32_16x16x16bf16_1k(ah[k8], bl, acc[nt], 0, 0, 0);
                acc[nt] = __builtin_amdgcn_mfma_f32_16x16x16bf16_1k(al[k8], bh, acc[nt], 0, 0, 0);
            }
        }
        const float* bq = branch ? bq2 : bq1;
        float* outp     = branch ? q2 : q1;
        float4 bv = *(const float4*)&bq[co0 + quad * 4];
        float bb[4] = {bv.x, bv.y, bv.z, bv.w};
#pragma unroll
        for (int nt = 0; nt < 8; ++nt) {
            int t = t0 + nt * 16 + l;
            float4 o = {acc[nt][0] + bb[0], acc[nt][1] + bb[1],
                        acc[nt][2] + bb[2], acc[nt][3] + bb[3]};
            *(float4*)&outp[(size_t)t * CC + co0 + quad * 4] = o;
        }
    }
}

// ---------------------------------------------------------------------------
// Kernel 2: FUSED attention — blocks 0-127 spectral (8 hw each), 128-375
// spatial ((d,h) slices). Rowsums via ones-MFMA (exact same truncated-bf16
// semantics as explicit persum). Gate column-sums fused. In-place.
// ---------------------------------------------------------------------------
#define QS2 132
#define QSS 20
#define QTP 1044
__global__ __launch_bounds__(1024, 8) void attn_kernel(
    float* __restrict__ q1, float* __restrict__ q2, float* __restrict__ sums)
{
    __shared__ __align__(16) ushort smem[HWW * QSS + HD * QTP];  // 74.4 KB
    __shared__ float fsum[CC];
    const int tid  = threadIdx.x;
    const int lane = tid & 63;
    const int l    = lane & 15;
    const int quad = lane >> 4;
    const float k2 = SCALE2 * 1.44269504f;
    const short4v onesb = {(short)0x3F80, (short)0x3F80, (short)0x3F80, (short)0x3F80};
    if (tid < CC) fsum[tid] = 0.f;

    if (blockIdx.x < 128) {
        // ---------------- spectral: 8 hw per block ----------------
        const int wave = tid >> 6;
        const int hwl  = wave >> 1;
        const int half = wave & 1;
        const int hw   = blockIdx.x * 8 + hwl;
        ushort* Q = smem + hwl * (32 * QS2);
        for (int it = 0; it < 8; ++it) {
            int idx = it * 64 + lane;
            int dd = half * 16 + (idx >> 5), c4 = idx & 31;
            if (dd < 31) {
                float4 v = *(const float4*)&q1[((size_t)dd * HWW + hw) * CC + c4 * 4];
                unsigned s0 = bf16rne(v.x), s1 = bf16rne(v.y);
                unsigned s2 = bf16rne(v.z), s3 = bf16rne(v.w);
                *(uint2*)&Q[dd * QS2 + c4 * 4] = make_uint2(s0 | (s1 << 16), s2 | (s3 << 16));
            }
        }
        if (half) for (int i = lane; i < 128; i += 64) Q[31 * QS2 + i] = 0;
        __syncthreads();

        const int hh = half * 4;
#pragma unroll
        for (int hl = 0; hl < 4; ++hl) {
            const int hc = (hh + hl) * HD;
            short4v qf[2];
            qf[0] = *(const short4v*)&Q[l * QS2 + hc + quad * 4];
            qf[1] = *(const short4v*)&Q[(16 + l) * QS2 + hc + quad * 4];
            short4v va[2];
#pragma unroll
            for (int j = 0; j < 2; ++j)
#pragma unroll
                for (int jj = 0; jj < 4; ++jj)
                    va[j][jj] = (short)Q[(j * 16 + quad * 4 + jj) * QS2 + hc + l];

            float4v o[2]   = {(float4v){0.f,0.f,0.f,0.f}, (float4v){0.f,0.f,0.f,0.f}};
            float4v osr[2] = {(float4v){0.f,0.f,0.f,0.f}, (float4v){0.f,0.f,0.f,0.f}};
#pragma unroll
            for (int j = 0; j < 2; ++j) {
#pragma unroll
                for (int i2 = 0; i2 < 2; ++i2) {
                    float4v s = __builtin_amdgcn_mfma_f32_16x16x16bf16_1k(
                        qf[j], qf[i2], (float4v){0.f,0.f,0.f,0.f}, 0, 0, 0);
                    unsigned u0 = __float_as_uint(__builtin_amdgcn_exp2f(s[0] * k2));
                    unsigned u1 = __float_as_uint(__builtin_amdgcn_exp2f(s[1] * k2));
                    unsigned u2 = __float_as_uint(__builtin_amdgcn_exp2f(s[2] * k2));
                    unsigned u3 = __float_as_uint(__builtin_amdgcn_exp2f(s[3] * k2));
                    if (j == 1 && quad == 3) u3 = 0;   // mask key 31
                    short4v pf;
                    pf[0] = (short)(u0 >> 16); pf[1] = (short)(u1 >> 16);
                    pf[2] = (short)(u2 >> 16); pf[3] = (short)(u3 >> 16);
                    o[i2]   = __builtin_amdgcn_mfma_f32_16x16x16bf16_1k(va[j], pf, o[i2], 0, 0, 0);
                    osr[i2] = __builtin_amdgcn_mfma_f32_16x16x16bf16_1k(onesb, pf, osr[i2], 0, 0, 0);
                }
            }
            float vsum[4] = {0.f, 0.f, 0.f, 0.f};
#pragma unroll
            for (int i2 = 0; i2 < 2; ++i2) {
                float inv = 1.f / osr[i2][0];   // rowsum(query=i2*16+l), this lane
                int dq = i2 * 16 + l;
                if (dq < 31) {
                    float4 ov = {o[i2][0]*inv, o[i2][1]*inv, o[i2][2]*inv, o[i2][3]*inv};
                    *(float4*)&q1[((size_t)dq * HWW + hw) * CC + hc + quad * 4] = ov;
#pragma unroll
                    for (int r = 0; r < 4; ++r) vsum[r] += o[i2][r] * inv;
                }
            }
#pragma unroll
            for (int r = 0; r < 4; ++r) {
                float v = vsum[r];
                v += __shfl_xor(v, 1); v += __shfl_xor(v, 2);
                v += __shfl_xor(v, 4); v += __shfl_xor(v, 8);
                if (l == 0) atomicAdd(&fsum[hc + quad * 4 + r], v);
            }
        }
        __syncthreads();
        if (tid < CC) atomicAdd(&sums[tid], fsum[tid]);
    } else {
        // ---------------- spatial: one (d,h) slice per block ----------------
        const int bidx = blockIdx.x - 128;
        const int d = bidx >> 3, h = bidx & 7;
        ushort* Qs  = smem;
        ushort* QTs = smem + HWW * QSS;
        const size_t base = (size_t)d * HWW * CC + h * HD;

        for (int i = tid; i < HWW * 4; i += 1024) {
            int row = i >> 2, q4 = i & 3;
            float4 v = *(const float4*)&q2[base + (size_t)row * CC + q4 * 4];
            unsigned s0 = bf16rne(v.x), s1 = bf16rne(v.y);
            unsigned s2 = bf16rne(v.z), s3 = bf16rne(v.w);
            *(uint2*)&Qs[row * QSS + q4 * 4] = make_uint2(s0 | (s1 << 16), s2 | (s3 << 16));
            QTs[(q4 * 4 + 0) * QTP + row] = (ushort)s0;
            QTs[(q4 * 4 + 1) * QTP + row] = (ushort)s1;
            QTs[(q4 * 4 + 2) * QTP + row] = (ushort)s2;
            QTs[(q4 * 4 + 3) * QTP + row] = (ushort)s3;
        }
        __syncthreads();

        const int Rw = (tid >> 6) * 64;
        short4v qf[4];
#pragma unroll
        for (int lt = 0; lt < 4; ++lt) {
            short4v raw = *(short4v*)&Qs[(Rw + lt * 16 + l) * QSS + quad * 4];
            short4v sc;
#pragma unroll
            for (int e = 0; e < 4; ++e) {
                float f = bf2f((unsigned)(ushort)raw[e]) * k2;
                sc[e] = (short)bf16rne(f);
            }
            qf[lt] = sc;
        }

        float4v acc[4], accs[4];
#pragma unroll
        for (int lt = 0; lt < 4; ++lt) {
            acc[lt]  = (float4v){0.f, 0.f, 0.f, 0.f};
            accs[lt] = (float4v){0.f, 0.f, 0.f, 0.f};
        }

#pragma unroll 2
        for (int mt = 0; mt < 64; ++mt) {
            const int m0 = mt * 16;
            short4v ka = *(short4v*)&Qs[(m0 + l) * QSS + quad * 4];
            short4v vb = *(short4v*)&QTs[l * QTP + m0 + quad * 4];
#pragma unroll
            for (int lt = 0; lt < 4; ++lt) {
                float4v s = __builtin_amdgcn_mfma_f32_16x16x16bf16_1k(
                    ka, qf[lt], (float4v){0.f, 0.f, 0.f, 0.f}, 0, 0, 0);
                unsigned u0 = __float_as_uint(__builtin_amdgcn_exp2f(s[0]));
                unsigned u1 = __float_as_uint(__builtin_amdgcn_exp2f(s[1]));
                unsigned u2 = __float_as_uint(__builtin_amdgcn_exp2f(s[2]));
                unsigned u3 = __float_as_uint(__builtin_amdgcn_exp2f(s[3]));
                short4v pf;
                pf[0] = (short)(u0 >> 16); pf[1] = (short)(u1 >> 16);
                pf[2] = (short)(u2 >> 16); pf[3] = (short)(u3 >> 16);
                acc[lt]  = __builtin_amdgcn_mfma_f32_16x16x16bf16_1k(pf, vb, acc[lt], 0, 0, 0);
                accs[lt] = __builtin_amdgcn_mfma_f32_16x16x16bf16_1k(pf, onesb, accs[lt], 0, 0, 0);
            }
        }

        float osum = 0.f;
#pragma unroll
        for (int lt = 0; lt < 4; ++lt) {
#pragma unroll
            for (int reg = 0; reg < 4; ++reg) {
                float val = acc[lt][reg] / accs[lt][reg];   // rowsum on this lane
                int row = Rw + lt * 16 + quad * 4 + reg;
                q2[base + (size_t)row * CC + l] = val;
                osum += val;
            }
        }
        osum += __shfl_xor(osum, 16);
        osum += __shfl_xor(osum, 32);
        if (quad == 0) atomicAdd(&fsum[l], osum);
        __syncthreads();
        if (tid < HD) atomicAdd(&sums[CC + h * HD + tid], fsum[tid]);
    }
}

// ---------------------------------------------------------------------------
// Kernel 3: gate via folded Wc/bc: g = sigmoid((sums·Wc)/TOK + bc).
// ---------------------------------------------------------------------------
__global__ __launch_bounds__(512) void gate_kernel(
    const float* __restrict__ sums, const float* __restrict__ Wc,
    const float* __restrict__ bc, float* __restrict__ gate)
{
    __shared__ float pa[4][CC];
    const int tid = threadIdx.x;
    const int part = tid >> 7;
    const int c = tid & 127;
    float a = 0.f;
    for (int kk = 0; kk < 64; ++kk) {
        int k = part * 64 + kk;
        a += sums[k] * Wc[(size_t)k * CC + c];
    }
    pa[part][c] = a;
    __syncthreads();
    if (part == 0) {
        float g = (pa[0][c] + pa[1][c] + pa[2][c] + pa[3][c]) * (1.f / (float)TOK) + bc[c];
        gate[c] = 1.f / (1.f + __expf(-g));
    }
}

// ---------------------------------------------------------------------------
// Kernel 4: output projection, BOTH branches per block, 64-token tiles.
// out[co][t] = g*(q1@Wp1 + bp1) + (1-g)*(q2@Wp2 + bp2)
// __launch_bounds__(512,2): avoid the 64-VGPR spill cap (see qproj note).
// ---------------------------------------------------------------------------
__global__ __launch_bounds__(512, 2) void oproj_kernel(
    const float* __restrict__ q1, const float* __restrict__ q2,
    const ushort* __restrict__ wsp,
    const float* __restrict__ bp1, const float* __restrict__ bp2,
    const float* __restrict__ gatev, float* __restrict__ out)
{
    __shared__ ushort Ahi[64 * AST], Alo[64 * AST];   // 33.8 KB
    const int tid = threadIdx.x;
    const int t0  = blockIdx.x * 64;
    const int lane = tid & 63;
    const int l    = lane & 15;
    const int quad = lane >> 4;
    const int co0  = (tid >> 6) * 16;

    float4v acc[2][4];
#pragma unroll
    for (int br = 0; br < 2; ++br)
#pragma unroll
        for (int nt = 0; nt < 4; ++nt) acc[br][nt] = (float4v){0.f, 0.f, 0.f, 0.f};

    for (int br = 0; br < 2; ++br) {
        const float* act = br ? q2 : q1;
        const ushort* Whi = wsp + (size_t)(2 + br) * 2 * CC * CC;
        const ushort* Wlo = Whi + CC * CC;
        short4v ah[8], al[8];
#pragma unroll
        for (int k8 = 0; k8 < 8; ++k8) {
            ah[k8] = *(const short4v*)&Whi[(co0 + l) * CC + k8 * 16 + quad * 4];
            al[k8] = *(const short4v*)&Wlo[(co0 + l) * CC + k8 * 16 + quad * 4];
        }
        __syncthreads();
        for (int i = tid; i < 64 * CC / 4; i += 512) {
            int k4 = i & 31, t = i >> 5;
            float4 v = *(const float4*)&act[(size_t)(t0 + t) * CC + k4 * 4];
            float xv[4] = {v.x, v.y, v.z, v.w};
            unsigned hi[4], lo[4];
#pragma unroll
            for (int e = 0; e < 4; ++e) {
                hi[e] = bf16rne(xv[e]);
                lo[e] = bf16rne(xv[e] - bf2f(hi[e]));
            }
            *(uint2*)&Ahi[t * AST + k4 * 4] = make_uint2(hi[0] | (hi[1] << 16), hi[2] | (hi[3] << 16));
            *(uint2*)&Alo[t * AST + k4 * 4] = make_uint2(lo[0] | (lo[1] << 16), lo[2] | (lo[3] << 16));
        }
        __syncthreads();
#pragma unroll
        for (int k8 = 0; k8 < 8; ++k8) {
#pragma unroll
            for (int nt = 0; nt < 4; ++nt) {
                short4v bh = *(const short4v*)&Ahi[(nt * 16 + l) * AST + k8 * 16 + quad * 4];
                short4v bl = *(const short4v*)&Alo[(nt * 16 + l) * AST + k8 * 16 + quad * 4];
                acc[br][nt] = __builtin_amdgcn_mfma_f32_16x16x16bf16_1k(ah[k8], bh, acc[br][nt], 0, 0, 0);
                acc[br][nt] = __builtin_amdgcn_mfma_f32_16x16x16bf16_1k(ah[k8], bl, acc[br][nt], 0, 0, 0);
                acc[br][nt] = __builtin_amdgcn_mfma_f32_16x16x16bf16_1k(al[k8], bh, acc[br][nt], 0, 0, 0);
            }
        }
    }

    float4 b1 = *(const float4*)&bp1[co0 + quad * 4];
    float4 b2 = *(const float4*)&bp2[co0 + quad * 4];
    float4 gv = *(const float4*)&gatev[co0 + quad * 4];
    float bb1[4] = {b1.x, b1.y, b1.z, b1.w};
    float bb2[4] = {b2.x, b2.y, b2.z, b2.w};
    float gg[4]  = {gv.x, gv.y, gv.z, gv.w};
#pragma unroll
    for (int nt = 0; nt < 4; ++nt) {
        int t = t0 + nt * 16 + l;
#pragma unroll
        for (int reg = 0; reg < 4; ++reg) {
            size_t idx = (size_t)(co0 + quad * 4 + reg) * TOK + t;
            out[idx] = gg[reg] * (acc[0][nt][reg] + bb1[reg]) +
                       (1.f - gg[reg]) * (acc[1][nt][reg] + bb2[reg]);
        }
    }
}

extern "C" void kernel_launch(void* const* d_in, const int* in_sizes, int n_in,
                              void* d_out, int out_size, void* d_ws, size_t ws_size,
                              hipStream_t stream)
{
    const float* x   = (const float*)d_in[0];
    const float* Wq1 = (const float*)d_in[1];
    const float* bq1 = (const float*)d_in[2];
    const float* Wp1 = (const float*)d_in[3];
    const float* bp1 = (const float*)d_in[4];
    const float* Wq2 = (const float*)d_in[5];
    const float* bq2 = (const float*)d_in[6];
    const float* Wp2 = (const float*)d_in[7];
    const float* bp2 = (const float*)d_in[8];
    const float* Wg  = (const float*)d_in[9];
    const float* bg  = (const float*)d_in[10];
    float* out = (float*)d_out;

    float*  q1   = (float*)d_ws;                 // spec q / attn-out (in-place)
    float*  q2   = q1 + (size_t)TOK * CC;        // spat q / attn-out (in-place)
    float*  sums = q2 + (size_t)TOK * CC;        // 256 floats
    float*  gate = sums + 2 * CC;                // 128 floats
    ushort* wsp  = (ushort*)(gate + CC);         // 4 x 2 x 128 x 128 ushorts
    float*  Wc   = (float*)(wsp + 4 * 2 * CC * CC);  // 256 x 128 floats
    float*  bc   = Wc + 2 * CC * CC;             // 128 floats

    hipMemsetAsync(sums, 0, 2 * CC * sizeof(float), stream);
    prep_kernel<<<dim3(193), 256, 0, stream>>>(Wq1, Wq2, Wp1, Wp2, Wg, bp1, bp2, bg,
                                               wsp, Wc, bc);
    qproj_kernel<<<dim3(248), 512, 0, stream>>>(x, wsp, bq1, bq2, q1, q2);
    attn_kernel<<<dim3(376), 1024, 0, stream>>>(q1, q2, sums);
    gate_kernel<<<1, 512, 0, stream>>>(sums, Wc, bc, gate);
    oproj_kernel<<<dim3(496), 512, 0, stream>>>(q1, q2, wsp, bp1, bp2, gate, out);
}

// Round 9
// 202.410 us; speedup vs baseline: 1.2125x; 1.0525x over previous
//
#include <hip/hip_runtime.h>
#include <cstddef>

#define CC 128
#define NH 8
#define HD 16
#define DDIM 31
#define HWW 1024
#define TOK 31744   // DDIM * HWW
#define SCALE2 0.0625f   // (HD^-0.5)^2 — both QK^T operands pre-scaled in the ref

typedef __attribute__((ext_vector_type(4))) short  short4v;
typedef __attribute__((ext_vector_type(4))) float  float4v;

__device__ inline unsigned bf16rne(float f) {
    unsigned u = __float_as_uint(f);
    return (u + 0x7fffu + ((u >> 16) & 1u)) >> 16;
}
__device__ inline float bf2f(unsigned h) { return __uint_as_float(h << 16); }

// Load this wave's W^T A-frags (16 co x 128 k) straight from global W[k][co],
// splitting to bf16 hi/lo in-register. 32 scalar loads per branch per wave;
// weights are L2/L3-hot across blocks. Replaces the prep_kernel round-trip.
__device__ inline void load_wfrags(const float* __restrict__ W, int co0, int l,
                                   int quad, short4v* ah, short4v* al)
{
#pragma unroll
    for (int k8 = 0; k8 < 8; ++k8) {
#pragma unroll
        for (int j = 0; j < 4; ++j) {
            float w = W[(size_t)(k8 * 16 + quad * 4 + j) * CC + co0 + l];
            unsigned h = bf16rne(w);
            ah[k8][j] = (short)h;
            al[k8][j] = (short)bf16rne(w - bf2f(h));
        }
    }
}

// ---------------------------------------------------------------------------
// Kernel 1: Q projection, BOTH branches per block (x staged once).
// q_b[t][co] = sum_ci x[ci][t] * Wq_b[ci][co] + bq_b[co]
// 3-term bf16x2 split (hi*hi + hi*lo + lo*hi). Block 0 zeroes the gate sums.
// (512,2): 256-VGPR budget — (512,4)'s 64-VGPR cap caused accumulator spills
// (r7: 310 MB scratch traffic). LDS 67.6 KB limits to 2 blocks/CU anyway.
// ---------------------------------------------------------------------------
#define AST 132   // LDS act row stride (ushorts)
__global__ __launch_bounds__(512, 2) void qproj_kernel(
    const float* __restrict__ x,
    const float* __restrict__ Wq1, const float* __restrict__ Wq2,
    const float* __restrict__ bq1, const float* __restrict__ bq2,
    float* __restrict__ q1, float* __restrict__ q2, float* __restrict__ sums)
{
    __shared__ ushort Ahi[CC * AST], Alo[CC * AST];   // [t][ci], 67.6 KB
    const int tid = threadIdx.x;
    const int t0  = blockIdx.x * 128;
    if (blockIdx.x == 0 && tid < 2 * CC) sums[tid] = 0.f;   // for attn's atomics

    // stage x tile transposed + split: [t][ci] (once, shared by both branches)
    for (int i = tid; i < CC * 128 / 4; i += 512) {
        int t4 = i & 31, ci = i >> 5;
        float4 v = *(const float4*)&x[(size_t)ci * TOK + t0 + t4 * 4];
        float xv[4] = {v.x, v.y, v.z, v.w};
#pragma unroll
        for (int e = 0; e < 4; ++e) {
            unsigned h = bf16rne(xv[e]);
            unsigned lw = bf16rne(xv[e] - bf2f(h));
            Ahi[(t4 * 4 + e) * AST + ci] = (ushort)h;
            Alo[(t4 * 4 + e) * AST + ci] = (ushort)lw;
        }
    }
    __syncthreads();

    const int lane = tid & 63;
    const int l    = lane & 15;
    const int quad = lane >> 4;
    const int co0  = (tid >> 6) * 16;

    for (int branch = 0; branch < 2; ++branch) {
        const float* W = branch ? Wq2 : Wq1;
        short4v ah[8], al[8];
        load_wfrags(W, co0, l, quad, ah, al);
        float4v acc[8];
#pragma unroll
        for (int nt = 0; nt < 8; ++nt) acc[nt] = (float4v){0.f, 0.f, 0.f, 0.f};
#pragma unroll
        for (int k8 = 0; k8 < 8; ++k8) {
#pragma unroll
            for (int nt = 0; nt < 8; ++nt) {
                short4v bh = *(const short4v*)&Ahi[(nt * 16 + l) * AST + k8 * 16 + quad * 4];
                short4v bl = *(const short4v*)&Alo[(nt * 16 + l) * AST + k8 * 16 + quad * 4];
                acc[nt] = __builtin_amdgcn_mfma_f32_16x16x16bf16_1k(ah[k8], bh, acc[nt], 0, 0, 0);
                acc[nt] = __builtin_amdgcn_mfma_f32_16x16x16bf16_1k(ah[k8], bl, acc[nt], 0, 0, 0);
                acc[nt] = __builtin_amdgcn_mfma_f32_16x16x16bf16_1k(al[k8], bh, acc[nt], 0, 0, 0);
            }
        }
        const float* bq = branch ? bq2 : bq1;
        float* outp     = branch ? q2 : q1;
        float4 bv = *(const float4*)&bq[co0 + quad * 4];
        float bb[4] = {bv.x, bv.y, bv.z, bv.w};
#pragma unroll
        for (int nt = 0; nt < 8; ++nt) {
            int t = t0 + nt * 16 + l;
            float4 o = {acc[nt][0] + bb[0], acc[nt][1] + bb[1],
                        acc[nt][2] + bb[2], acc[nt][3] + bb[3]};
            *(float4*)&outp[(size_t)t * CC + co0 + quad * 4] = o;
        }
    }
}

// ---------------------------------------------------------------------------
// Kernel 2: FUSED attention, grid 248 (<=256 CUs -> guaranteed single round).
// Phase 1: spatial slice (d=bid>>3, h=bid&7) — proven r8 numerics verbatim.
// Phase 2: 128 spectral jobs (8 hw x 8 heads each) distributed over the same
// blocks (even blocks 0..246 take jobs 0..123; odd blocks 1,3,5,7 take
// 124..127), reusing smem after a barrier. Rowsums via ones-MFMA (sums the
// truncated-bf16 P exactly — softmax bias cancellation preserved). Gate
// column-sums fused. In-place on q1/q2.
// ---------------------------------------------------------------------------
#define QS2 132
#define QSS 20
#define QTP 1044
__global__ __launch_bounds__(1024, 4) void attn_kernel(
    float* __restrict__ q1, float* __restrict__ q2, float* __restrict__ sums)
{
    __shared__ __align__(16) ushort smem[HWW * QSS + HD * QTP];  // 74.4 KB
    __shared__ float fsum[CC];
    const int tid  = threadIdx.x;
    const int lane = tid & 63;
    const int l    = lane & 15;
    const int quad = lane >> 4;
    const float k2 = SCALE2 * 1.44269504f;
    const short4v onesb = {(short)0x3F80, (short)0x3F80, (short)0x3F80, (short)0x3F80};
    if (tid < CC) fsum[tid] = 0.f;

    // ---------------- phase 1: spatial slice ----------------
    {
        const int d = blockIdx.x >> 3, h = blockIdx.x & 7;
        ushort* Qs  = smem;
        ushort* QTs = smem + HWW * QSS;
        const size_t base = (size_t)d * HWW * CC + h * HD;

        for (int i = tid; i < HWW * 4; i += 1024) {
            int row = i >> 2, q4 = i & 3;
            float4 v = *(const float4*)&q2[base + (size_t)row * CC + q4 * 4];
            unsigned s0 = bf16rne(v.x), s1 = bf16rne(v.y);
            unsigned s2 = bf16rne(v.z), s3 = bf16rne(v.w);
            *(uint2*)&Qs[row * QSS + q4 * 4] = make_uint2(s0 | (s1 << 16), s2 | (s3 << 16));
            QTs[(q4 * 4 + 0) * QTP + row] = (ushort)s0;
            QTs[(q4 * 4 + 1) * QTP + row] = (ushort)s1;
            QTs[(q4 * 4 + 2) * QTP + row] = (ushort)s2;
            QTs[(q4 * 4 + 3) * QTP + row] = (ushort)s3;
        }
        __syncthreads();

        const int Rw = (tid >> 6) * 64;
        short4v qf[4];
#pragma unroll
        for (int lt = 0; lt < 4; ++lt) {
            short4v raw = *(short4v*)&Qs[(Rw + lt * 16 + l) * QSS + quad * 4];
            short4v sc;
#pragma unroll
            for (int e = 0; e < 4; ++e) {
                float f = bf2f((unsigned)(ushort)raw[e]) * k2;
                sc[e] = (short)bf16rne(f);
            }
            qf[lt] = sc;
        }

        float4v acc[4], accs[4];
#pragma unroll
        for (int lt = 0; lt < 4; ++lt) {
            acc[lt]  = (float4v){0.f, 0.f, 0.f, 0.f};
            accs[lt] = (float4v){0.f, 0.f, 0.f, 0.f};
        }

#pragma unroll 2
        for (int mt = 0; mt < 64; ++mt) {
            const int m0 = mt * 16;
            short4v ka = *(short4v*)&Qs[(m0 + l) * QSS + quad * 4];
            short4v vb = *(short4v*)&QTs[l * QTP + m0 + quad * 4];
#pragma unroll
            for (int lt = 0; lt < 4; ++lt) {
                float4v s = __builtin_amdgcn_mfma_f32_16x16x16bf16_1k(
                    ka, qf[lt], (float4v){0.f, 0.f, 0.f, 0.f}, 0, 0, 0);
                unsigned u0 = __float_as_uint(__builtin_amdgcn_exp2f(s[0]));
                unsigned u1 = __float_as_uint(__builtin_amdgcn_exp2f(s[1]));
                unsigned u2 = __float_as_uint(__builtin_amdgcn_exp2f(s[2]));
                unsigned u3 = __float_as_uint(__builtin_amdgcn_exp2f(s[3]));
                short4v pf;
                pf[0] = (short)(u0 >> 16); pf[1] = (short)(u1 >> 16);
                pf[2] = (short)(u2 >> 16); pf[3] = (short)(u3 >> 16);
                acc[lt]  = __builtin_amdgcn_mfma_f32_16x16x16bf16_1k(pf, vb, acc[lt], 0, 0, 0);
                accs[lt] = __builtin_amdgcn_mfma_f32_16x16x16bf16_1k(pf, onesb, accs[lt], 0, 0, 0);
            }
        }

        float osum = 0.f;
#pragma unroll
        for (int lt = 0; lt < 4; ++lt) {
#pragma unroll
            for (int reg = 0; reg < 4; ++reg) {
                float val = acc[lt][reg] / accs[lt][reg];   // rowsum on this lane
                int row = Rw + lt * 16 + quad * 4 + reg;
                q2[base + (size_t)row * CC + l] = val;
                osum += val;
            }
        }
        osum += __shfl_xor(osum, 16);
        osum += __shfl_xor(osum, 32);
        if (quad == 0) atomicAdd(&fsum[l], osum);
        __syncthreads();
        if (tid < HD) atomicAdd(&sums[CC + h * HD + tid], fsum[tid]);
    }

    // ---------------- phase 2: spectral job (if assigned) ----------------
    const int half_id = blockIdx.x >> 1;
    const bool has_job = (blockIdx.x & 1) ? (half_id < 4) : (half_id < 124);
    if (!has_job) return;
    const int job = (blockIdx.x & 1) ? (124 + half_id) : half_id;
    const int hw0 = job * 8;

    __syncthreads();                       // phase-1 smem reads + fsum use done
    if (tid < CC) fsum[tid] = 0.f;

    const int wave = tid >> 6;
    const int hwl  = wave >> 1;
    const int half = wave & 1;
    const int hw   = hw0 + hwl;
    ushort* Q = smem + hwl * (32 * QS2);
    for (int it = 0; it < 8; ++it) {
        int idx = it * 64 + lane;
        int dd = half * 16 + (idx >> 5), c4 = idx & 31;
        if (dd < 31) {
            float4 v = *(const float4*)&q1[((size_t)dd * HWW + hw) * CC + c4 * 4];
            unsigned s0 = bf16rne(v.x), s1 = bf16rne(v.y);
            unsigned s2 = bf16rne(v.z), s3 = bf16rne(v.w);
            *(uint2*)&Q[dd * QS2 + c4 * 4] = make_uint2(s0 | (s1 << 16), s2 | (s3 << 16));
        }
    }
    if (half) for (int i = lane; i < 128; i += 64) Q[31 * QS2 + i] = 0;
    __syncthreads();

    const int hh = half * 4;
#pragma unroll
    for (int hl = 0; hl < 4; ++hl) {
        const int hc = (hh + hl) * HD;
        short4v qf[2];
        qf[0] = *(const short4v*)&Q[l * QS2 + hc + quad * 4];
        qf[1] = *(const short4v*)&Q[(16 + l) * QS2 + hc + quad * 4];
        short4v va[2];
#pragma unroll
        for (int j = 0; j < 2; ++j)
#pragma unroll
            for (int jj = 0; jj < 4; ++jj)
                va[j][jj] = (short)Q[(j * 16 + quad * 4 + jj) * QS2 + hc + l];

        float4v o[2]   = {(float4v){0.f,0.f,0.f,0.f}, (float4v){0.f,0.f,0.f,0.f}};
        float4v osr[2] = {(float4v){0.f,0.f,0.f,0.f}, (float4v){0.f,0.f,0.f,0.f}};
#pragma unroll
        for (int j = 0; j < 2; ++j) {
#pragma unroll
            for (int i2 = 0; i2 < 2; ++i2) {
                float4v s = __builtin_amdgcn_mfma_f32_16x16x16bf16_1k(
                    qf[j], qf[i2], (float4v){0.f,0.f,0.f,0.f}, 0, 0, 0);
                unsigned u0 = __float_as_uint(__builtin_amdgcn_exp2f(s[0] * k2));
                unsigned u1 = __float_as_uint(__builtin_amdgcn_exp2f(s[1] * k2));
                unsigned u2 = __float_as_uint(__builtin_amdgcn_exp2f(s[2] * k2));
                unsigned u3 = __float_as_uint(__builtin_amdgcn_exp2f(s[3] * k2));
                if (j == 1 && quad == 3) u3 = 0;   // mask key 31
                short4v pf;
                pf[0] = (short)(u0 >> 16); pf[1] = (short)(u1 >> 16);
                pf[2] = (short)(u2 >> 16); pf[3] = (short)(u3 >> 16);
                o[i2]   = __builtin_amdgcn_mfma_f32_16x16x16bf16_1k(va[j], pf, o[i2], 0, 0, 0);
                osr[i2] = __builtin_amdgcn_mfma_f32_16x16x16bf16_1k(onesb, pf, osr[i2], 0, 0, 0);
            }
        }
        float vsum[4] = {0.f, 0.f, 0.f, 0.f};
#pragma unroll
        for (int i2 = 0; i2 < 2; ++i2) {
            float inv = 1.f / osr[i2][0];   // rowsum(query=i2*16+l), this lane
            int dq = i2 * 16 + l;
            if (dq < 31) {
                float4 ov = {o[i2][0]*inv, o[i2][1]*inv, o[i2][2]*inv, o[i2][3]*inv};
                *(float4*)&q1[((size_t)dq * HWW + hw) * CC + hc + quad * 4] = ov;
#pragma unroll
                for (int r = 0; r < 4; ++r) vsum[r] += o[i2][r] * inv;
            }
        }
#pragma unroll
        for (int r = 0; r < 4; ++r) {
            float v = vsum[r];
            v += __shfl_xor(v, 1); v += __shfl_xor(v, 2);
            v += __shfl_xor(v, 4); v += __shfl_xor(v, 8);
            if (l == 0) atomicAdd(&fsum[hc + quad * 4 + r], v);
        }
    }
    __syncthreads();
    if (tid < CC) atomicAdd(&sums[tid], fsum[tid]);
}

// ---------------------------------------------------------------------------
// Kernel 3: output projection + in-block gate, BOTH branches, 64-token tiles.
// Gate (exact reference math): gi = [sums1/TOK@Wp1+bp1 ; sums2/TOK@Wp2+bp2],
// g = sigmoid(gi@Wg + bg) — computed per block before the GEMM (latency
// hidden). out[co][t] = g*(q1@Wp1+bp1) + (1-g)*(q2@Wp2+bp2).
// ---------------------------------------------------------------------------
__global__ __launch_bounds__(512, 2) void oproj_kernel(
    const float* __restrict__ q1, const float* __restrict__ q2,
    const float* __restrict__ Wp1, const float* __restrict__ Wp2,
    const float* __restrict__ bp1, const float* __restrict__ bp2,
    const float* __restrict__ Wg,  const float* __restrict__ bg,
    const float* __restrict__ sums, float* __restrict__ out)
{
    __shared__ ushort Ahi[64 * AST], Alo[64 * AST];   // 33.8 KB
    __shared__ float pa[4][CC];
    __shared__ float giv[2 * CC];
    __shared__ float gf[CC];
    const int tid = threadIdx.x;
    const int t0  = blockIdx.x * 64;
    const int lane = tid & 63;
    const int l    = lane & 15;
    const int quad = lane >> 4;
    const int co0  = (tid >> 6) * 16;

    // ---- gate phase (two-stage GEMV from sums) ----
    {
        const int part = tid >> 7, c = tid & 127;
        const float* Wp = (part < 2) ? Wp1 : Wp2;
        const float* sp = (part < 2) ? sums : sums + CC;
        const int k0 = (part & 1) * 64;
        float a = 0.f;
        for (int kk = 0; kk < 64; ++kk) {
            int k = k0 + kk;
            a += sp[k] * Wp[(size_t)k * CC + c];
        }
        pa[part][c] = a;
        __syncthreads();
        if (tid < 2 * CC) {
            float m = (tid < CC) ? (pa[0][tid] + pa[1][tid])
                                 : (pa[2][tid - CC] + pa[3][tid - CC]);
            float bb = (tid < CC) ? bp1[tid] : bp2[tid - CC];
            giv[tid] = m * (1.f / (float)TOK) + bb;
        }
        __syncthreads();
        float b = 0.f;
        for (int kk = 0; kk < 64; ++kk) {
            int j = part * 64 + kk;
            b += giv[j] * Wg[(size_t)j * CC + c];
        }
        pa[part][c] = b;
        __syncthreads();
        if (tid < CC)
            gf[tid] = 1.f / (1.f + __expf(-(bg[tid] + pa[0][tid] + pa[1][tid] +
                                           pa[2][tid] + pa[3][tid])));
    }

    // ---- main GEMM ----
    float4v acc[2][4];
#pragma unroll
    for (int br = 0; br < 2; ++br)
#pragma unroll
        for (int nt = 0; nt < 4; ++nt) acc[br][nt] = (float4v){0.f, 0.f, 0.f, 0.f};

    for (int br = 0; br < 2; ++br) {
        const float* act = br ? q2 : q1;
        const float* W   = br ? Wp2 : Wp1;
        short4v ah[8], al[8];
        load_wfrags(W, co0, l, quad, ah, al);
        __syncthreads();   // previous phase/branch LDS reads done
        for (int i = tid; i < 64 * CC / 4; i += 512) {
            int k4 = i & 31, t = i >> 5;
            float4 v = *(const float4*)&act[(size_t)(t0 + t) * CC + k4 * 4];
            float xv[4] = {v.x, v.y, v.z, v.w};
            unsigned hi[4], lo[4];
#pragma unroll
            for (int e = 0; e < 4; ++e) {
                hi[e] = bf16rne(xv[e]);
                lo[e] = bf16rne(xv[e] - bf2f(hi[e]));
            }
            *(uint2*)&Ahi[t * AST + k4 * 4] = make_uint2(hi[0] | (hi[1] << 16), hi[2] | (hi[3] << 16));
            *(uint2*)&Alo[t * AST + k4 * 4] = make_uint2(lo[0] | (lo[1] << 16), lo[2] | (lo[3] << 16));
        }
        __syncthreads();
#pragma unroll
        for (int k8 = 0; k8 < 8; ++k8) {
#pragma unroll
            for (int nt = 0; nt < 4; ++nt) {
                short4v bh = *(const short4v*)&Ahi[(nt * 16 + l) * AST + k8 * 16 + quad * 4];
                short4v bl = *(const short4v*)&Alo[(nt * 16 + l) * AST + k8 * 16 + quad * 4];
                acc[br][nt] = __builtin_amdgcn_mfma_f32_16x16x16bf16_1k(ah[k8], bh, acc[br][nt], 0, 0, 0);
                acc[br][nt] = __builtin_amdgcn_mfma_f32_16x16x16bf16_1k(ah[k8], bl, acc[br][nt], 0, 0, 0);
                acc[br][nt] = __builtin_amdgcn_mfma_f32_16x16x16bf16_1k(al[k8], bh, acc[br][nt], 0, 0, 0);
            }
        }
    }

    float4 b1 = *(const float4*)&bp1[co0 + quad * 4];
    float4 b2 = *(const float4*)&bp2[co0 + quad * 4];
    float bb1[4] = {b1.x, b1.y, b1.z, b1.w};
    float bb2[4] = {b2.x, b2.y, b2.z, b2.w};
    float gg[4];
#pragma unroll
    for (int e = 0; e < 4; ++e) gg[e] = gf[co0 + quad * 4 + e];
#pragma unroll
    for (int nt = 0; nt < 4; ++nt) {
        int t = t0 + nt * 16 + l;
#pragma unroll
        for (int reg = 0; reg < 4; ++reg) {
            size_t idx = (size_t)(co0 + quad * 4 + reg) * TOK + t;
            out[idx] = gg[reg] * (acc[0][nt][reg] + bb1[reg]) +
                       (1.f - gg[reg]) * (acc[1][nt][reg] + bb2[reg]);
        }
    }
}

extern "C" void kernel_launch(void* const* d_in, const int* in_sizes, int n_in,
                              void* d_out, int out_size, void* d_ws, size_t ws_size,
                              hipStream_t stream)
{
    const float* x   = (const float*)d_in[0];
    const float* Wq1 = (const float*)d_in[1];
    const float* bq1 = (const float*)d_in[2];
    const float* Wp1 = (const float*)d_in[3];
    const float* bp1 = (const float*)d_in[4];
    const float* Wq2 = (const float*)d_in[5];
    const float* bq2 = (const float*)d_in[6];
    const float* Wp2 = (const float*)d_in[7];
    const float* bp2 = (const float*)d_in[8];
    const float* Wg  = (const float*)d_in[9];
    const float* bg  = (const float*)d_in[10];
    float* out = (float*)d_out;

    float* q1   = (float*)d_ws;                 // spec q / attn-out (in-place)
    float* q2   = q1 + (size_t)TOK * CC;        // spat q / attn-out (in-place)
    float* sums = q2 + (size_t)TOK * CC;        // 256 floats (zeroed by qproj)

    qproj_kernel<<<dim3(248), 512, 0, stream>>>(x, Wq1, Wq2, bq1, bq2, q1, q2, sums);
    attn_kernel<<<dim3(248), 1024, 0, stream>>>(q1, q2, sums);
    oproj_kernel<<<dim3(496), 512, 0, stream>>>(q1, q2, Wp1, Wp2, bp1, bp2, Wg, bg,
                                                sums, out);
}